// Round 2
// baseline (1547.560 us; speedup 1.0000x reference)
//
#include <hip/hip_runtime.h>
#include <math.h>

#define NN 2048
#define HID 128
#define HID2 64
#define NP ((NN*(NN-1))/2)   // 2096128

// Kernel 1: per node row, fused h = relu(X@Wt + bt); A = h@W1[:128] + b1; B = h@W1[128:]
__global__ __launch_bounds__(128) void precompute_AB(
    const float* __restrict__ X, const float* __restrict__ Wt, const float* __restrict__ bt,
    const float* __restrict__ W1, const float* __restrict__ b1,
    float* __restrict__ A, float* __restrict__ B)
{
    __shared__ float x_s[HID];
    __shared__ float h_s[HID];
    const int row = blockIdx.x;
    const int c = threadIdx.x;
    x_s[c] = X[row*HID + c];
    __syncthreads();
    float hc = bt[c];
    #pragma unroll 8
    for (int k = 0; k < HID; ++k) hc = fmaf(x_s[k], Wt[k*HID + c], hc);
    h_s[c] = fmaxf(hc, 0.f);
    __syncthreads();
    float a = b1[c];
    float bsum = 0.f;
    #pragma unroll 8
    for (int k = 0; k < HID; ++k) {
        float hk = h_s[k];
        a    = fmaf(hk, W1[k*HID + c], a);
        bsum = fmaf(hk, W1[(HID + k)*HID + c], bsum);
    }
    A[row*HID + c] = a;
    B[row*HID + c] = bsum;
}

// Kernel 2: one thread per (i,j) pair.
// zn[128] lives in VGPRs (static indexing only); acc[64] lives in VGPRs.
// W2 / ln_g / ln_b / b2 / W3 accesses are wave-uniform -> scalar loads.
__global__ __launch_bounds__(256, 2) void pairs_kernel(
    const float* __restrict__ A, const float* __restrict__ B,
    const float* __restrict__ ln_g, const float* __restrict__ ln_b,
    const float* __restrict__ W2, const float* __restrict__ b2,
    const float* __restrict__ W3, const float* __restrict__ b3,
    float* __restrict__ out)
{
    __shared__ float a_s[HID];
    const int i = blockIdx.y;
    const int j = blockIdx.x * 256 + threadIdx.x;
    if (threadIdx.x < HID) a_s[threadIdx.x] = A[i*HID + threadIdx.x];
    __syncthreads();

    float* probs = out;
    float* pi    = out + NP;
    float* adj   = out + 3*(size_t)NP;

    if (j == i) {
        adj[(size_t)i*NN + i] = 0.f;   // diagonal
    }
    if (j <= i || j >= NN) return;

    const float4* __restrict__ B4 = (const float4*)(B + (size_t)j * HID);

    // z = A[i] + B[j], kept in registers
    float zn[HID];
    #pragma unroll
    for (int k4 = 0; k4 < HID/4; ++k4) {
        float4 b4 = B4[k4];
        zn[4*k4+0] = a_s[4*k4+0] + b4.x;
        zn[4*k4+1] = a_s[4*k4+1] + b4.y;
        zn[4*k4+2] = a_s[4*k4+2] + b4.z;
        zn[4*k4+3] = a_s[4*k4+3] + b4.w;
    }

    // LN stats
    float s1 = 0.f, s2 = 0.f;
    #pragma unroll
    for (int k = 0; k < HID; ++k) {
        s1 += zn[k];
        s2 = fmaf(zn[k], zn[k], s2);
    }
    const float mu   = s1 * (1.f/HID);
    const float var  = s2 * (1.f/HID) - mu*mu;
    const float rstd = rsqrtf(var + 1e-5f);

    // normalize + relu in place (uniform ln_g/ln_b -> s_load)
    #pragma unroll
    for (int k = 0; k < HID; ++k) {
        zn[k] = fmaxf(fmaf((zn[k] - mu) * rstd, ln_g[k], ln_b[k]), 0.f);
    }

    // acc = zn @ W2 + b2 ; W2 row is wave-uniform -> scalar loads
    float acc[HID2];
    #pragma unroll
    for (int c = 0; c < HID2; ++c) acc[c] = b2[c];
    #pragma unroll 2
    for (int k = 0; k < HID; ++k) {
        const float z = zn[k];
        #pragma unroll
        for (int c = 0; c < HID2; ++c) acc[c] = fmaf(z, W2[k*HID2 + c], acc[c]);
    }

    float logit = b3[0];
    #pragma unroll
    for (int c = 0; c < HID2; ++c) logit = fmaf(fmaxf(acc[c], 0.f), W3[c], logit);

    const float p = 1.f / (1.f + __expf(-logit));

    const int kpair = i*(NN-1) - (i*(i-1))/2 + (j - i - 1);
    probs[kpair]    = p;
    pi[kpair]       = (float)i;
    pi[NP + kpair]  = (float)j;
    adj[(size_t)i*NN + j] = p;
    adj[(size_t)j*NN + i] = p;
}

extern "C" void kernel_launch(void* const* d_in, const int* in_sizes, int n_in,
                              void* d_out, int out_size, void* d_ws, size_t ws_size,
                              hipStream_t stream) {
    const float* X    = (const float*)d_in[0];
    const float* Wt   = (const float*)d_in[1];
    const float* bt   = (const float*)d_in[2];
    const float* W1   = (const float*)d_in[3];
    const float* b1   = (const float*)d_in[4];
    const float* ln_g = (const float*)d_in[5];
    const float* ln_b = (const float*)d_in[6];
    const float* W2   = (const float*)d_in[7];
    const float* b2   = (const float*)d_in[8];
    const float* W3   = (const float*)d_in[9];
    const float* b3   = (const float*)d_in[10];
    float* out = (float*)d_out;

    float* A = (float*)d_ws;                  // [2048][128]
    float* B = A + (size_t)NN * HID;          // [2048][128]

    precompute_AB<<<NN, HID, 0, stream>>>(X, Wt, bt, W1, b1, A, B);
    pairs_kernel<<<dim3(NN/256, NN), 256, 0, stream>>>(A, B, ln_g, ln_b, W2, b2, W3, b3, out);
}

// Round 3
// 551.228 us; speedup vs baseline: 2.8075x; 2.8075x over previous
//
#include <hip/hip_runtime.h>
#include <math.h>

#define NN 2048
#define HID 128
#define HID2 64
#define NP ((NN*(NN-1))/2)   // 2096128

typedef __bf16 bf16x8 __attribute__((ext_vector_type(8)));
typedef float  f32x4  __attribute__((ext_vector_type(4)));

// Kernel 1: per node row, fused h = relu(X@Wt + bt); A = h@W1[:128] + b1; B = h@W1[128:]
__global__ __launch_bounds__(128) void precompute_AB(
    const float* __restrict__ X, const float* __restrict__ Wt, const float* __restrict__ bt,
    const float* __restrict__ W1, const float* __restrict__ b1,
    float* __restrict__ A, float* __restrict__ B)
{
    __shared__ float x_s[HID];
    __shared__ float h_s[HID];
    const int row = blockIdx.x;
    const int c = threadIdx.x;
    x_s[c] = X[row*HID + c];
    __syncthreads();
    float hc = bt[c];
    #pragma unroll 8
    for (int k = 0; k < HID; ++k) hc = fmaf(x_s[k], Wt[k*HID + c], hc);
    h_s[c] = fmaxf(hc, 0.f);
    __syncthreads();
    float a = b1[c];
    float bsum = 0.f;
    #pragma unroll 8
    for (int k = 0; k < HID; ++k) {
        float hk = h_s[k];
        a    = fmaf(hk, W1[k*HID + c], a);
        bsum = fmaf(hk, W1[(HID + k)*HID + c], bsum);
    }
    A[row*HID + c] = a;
    B[row*HID + c] = bsum;
}

// Kernel 1b: pack W2 (fp32 [128][64]) into bf16 B-fragment order for
// mfma_f32_16x16x32_bf16: frag (ks,nt), lane l, elem e  <-  W2[ks*32+(l>>4)*8+e][nt*16+(l&15)]
__global__ __launch_bounds__(256) void pack_W2(const float* __restrict__ W2,
                                               __bf16* __restrict__ W2p)
{
    const int t = threadIdx.x;
    for (int fs = t; fs < 16*64; fs += 256) {   // 16 frags x 64 lanes
        const int frag = fs >> 6, lane = fs & 63;
        const int ks = frag >> 2, nt = frag & 3;
        const int kbase = ks*32 + (lane >> 4)*8;
        const int col   = nt*16 + (lane & 15);
        #pragma unroll
        for (int e = 0; e < 8; ++e)
            W2p[fs*8 + e] = (__bf16)W2[(kbase + e)*HID2 + col];
    }
}

// Kernel 2: block = (i, 64 j's), 4 waves x 16 j's. No LDS, no barriers.
// Each lane computes zn in A-fragment layout; MFMA vs packed W2; epilogue reduces.
__global__ __launch_bounds__(256) void pairs_mfma(
    const float* __restrict__ A, const float* __restrict__ B,
    const float* __restrict__ ln_g, const float* __restrict__ ln_b,
    const __bf16* __restrict__ W2p, const float* __restrict__ b2,
    const float* __restrict__ W3, const float* __restrict__ b3,
    float* __restrict__ out)
{
    const int i  = blockIdx.y;
    const int j0 = blockIdx.x * 64;
    if (j0 + 63 < i) return;                 // block entirely below diagonal
    const int tid  = threadIdx.x;
    const int w    = tid >> 6;
    const int lane = tid & 63;
    const int jw0  = j0 + w*16;              // this wave's 16 j-rows
    if (jw0 + 15 < i) return;                // wave entirely below diagonal

    const int row = lane & 15;               // MFMA A row (pair within wave)
    const int g4  = lane >> 4;               // k-subgroup
    const int j   = jw0 + row;

    const float* __restrict__ Ar = A + (size_t)i * HID;
    const float* __restrict__ Br = B + (size_t)j * HID;

    // z = A[i] + B[j], in A-fragment layout: z[ks][e] = z_k at k = ks*32 + g4*8 + e
    float z[4][8];
    #pragma unroll
    for (int ks = 0; ks < 4; ++ks) {
        const int kb = ks*32 + g4*8;
        f32x4 a0 = *(const f32x4*)(Ar + kb);
        f32x4 a1 = *(const f32x4*)(Ar + kb + 4);
        f32x4 b0 = *(const f32x4*)(Br + kb);
        f32x4 b1 = *(const f32x4*)(Br + kb + 4);
        #pragma unroll
        for (int e = 0; e < 4; ++e) { z[ks][e] = a0[e] + b0[e]; z[ks][4+e] = a1[e] + b1[e]; }
    }

    // LN stats: full row lives in the 4 lanes {lane, lane^16, lane^32, lane^48}
    float s1 = 0.f, s2 = 0.f;
    #pragma unroll
    for (int ks = 0; ks < 4; ++ks)
        #pragma unroll
        for (int e = 0; e < 8; ++e) { s1 += z[ks][e]; s2 = fmaf(z[ks][e], z[ks][e], s2); }
    s1 += __shfl_xor(s1, 16); s1 += __shfl_xor(s1, 32);
    s2 += __shfl_xor(s2, 16); s2 += __shfl_xor(s2, 32);
    const float mu   = s1 * (1.f/HID);
    const float rstd = rsqrtf(s2*(1.f/HID) - mu*mu + 1e-5f);

    // normalize + relu + convert -> A fragments
    bf16x8 af[4];
    #pragma unroll
    for (int ks = 0; ks < 4; ++ks) {
        const int kb = ks*32 + g4*8;
        f32x4 g0 = *(const f32x4*)(ln_g + kb);
        f32x4 g1 = *(const f32x4*)(ln_g + kb + 4);
        f32x4 l0 = *(const f32x4*)(ln_b + kb);
        f32x4 l1 = *(const f32x4*)(ln_b + kb + 4);
        #pragma unroll
        for (int e = 0; e < 4; ++e) {
            float zn0 = fmaxf(fmaf((z[ks][e]   - mu) * rstd, g0[e], l0[e]), 0.f);
            float zn1 = fmaxf(fmaf((z[ks][4+e] - mu) * rstd, g1[e], l1[e]), 0.f);
            af[ks][e]   = (__bf16)zn0;
            af[ks][4+e] = (__bf16)zn1;
        }
    }

    // MFMA: acc[nt] (16 pairs x 16 channels), K = 128 over 4 steps
    f32x4 acc[4];
    #pragma unroll
    for (int nt = 0; nt < 4; ++nt) acc[nt] = (f32x4){0.f, 0.f, 0.f, 0.f};
    #pragma unroll
    for (int ks = 0; ks < 4; ++ks) {
        #pragma unroll
        for (int nt = 0; nt < 4; ++nt) {
            bf16x8 wf = *(const bf16x8*)(W2p + ((size_t)((ks*4 + nt)*64 + lane)) * 8);
            acc[nt] = __builtin_amdgcn_mfma_f32_16x16x32_bf16(af[ks], wf, acc[nt], 0, 0, 0);
        }
    }

    // epilogue: relu(acc + b2) . W3, reduced over 64 channels.
    // D layout: channel = nt*16 + (lane&15), pair row = (lane>>4)*4 + r
    float part[4] = {0.f, 0.f, 0.f, 0.f};
    #pragma unroll
    for (int nt = 0; nt < 4; ++nt) {
        const float b2c = b2[nt*16 + (lane & 15)];
        const float w3c = W3[nt*16 + (lane & 15)];
        #pragma unroll
        for (int r = 0; r < 4; ++r)
            part[r] = fmaf(fmaxf(acc[nt][r] + b2c, 0.f), w3c, part[r]);
    }
    #pragma unroll
    for (int m = 1; m <= 8; m <<= 1) {
        #pragma unroll
        for (int r = 0; r < 4; ++r) part[r] += __shfl_xor(part[r], m);
    }
    // lane l wants pair p = l&15 (held as reg p&3 in group p>>2); source lane s = (p>>2)*16 + (p&3)
    const int r_own = lane & 3;
    float val = (r_own == 0) ? part[0] : (r_own == 1) ? part[1] : (r_own == 2) ? part[2] : part[3];
    const int p = lane & 15;
    float x = __shfl(val, (p >> 2)*16 + (p & 3));

    if (lane < 16) {
        const int jj = jw0 + lane;
        float* probs = out;
        float* pi    = out + NP;
        float* adj   = out + 3*(size_t)NP;
        if (jj == i) {
            adj[(size_t)i*NN + i] = 0.f;
        } else if (jj > i) {
            const float logit = x + b3[0];
            const float pr = 1.f / (1.f + __expf(-logit));
            const int kpair = i*(NN-1) - (i*(i-1))/2 + (jj - i - 1);
            probs[kpair]   = pr;
            pi[kpair]      = (float)i;
            pi[NP + kpair] = (float)jj;
            adj[(size_t)i*NN + jj] = pr;
            adj[(size_t)jj*NN + i] = pr;
        }
    }
}

extern "C" void kernel_launch(void* const* d_in, const int* in_sizes, int n_in,
                              void* d_out, int out_size, void* d_ws, size_t ws_size,
                              hipStream_t stream) {
    const float* X    = (const float*)d_in[0];
    const float* Wt   = (const float*)d_in[1];
    const float* bt   = (const float*)d_in[2];
    const float* W1   = (const float*)d_in[3];
    const float* b1   = (const float*)d_in[4];
    const float* ln_g = (const float*)d_in[5];
    const float* ln_b = (const float*)d_in[6];
    const float* W2   = (const float*)d_in[7];
    const float* b2   = (const float*)d_in[8];
    const float* W3   = (const float*)d_in[9];
    const float* b3   = (const float*)d_in[10];
    float* out = (float*)d_out;

    float*  A   = (float*)d_ws;                      // [2048][128] f32
    float*  Bm  = A + (size_t)NN * HID;              // [2048][128] f32
    __bf16* W2p = (__bf16*)(Bm + (size_t)NN * HID);  // 16 frags x 64 lanes x 8 bf16

    precompute_AB<<<NN, HID, 0, stream>>>(X, Wt, bt, W1, b1, A, Bm);
    pack_W2<<<1, 256, 0, stream>>>(W2, W2p);
    pairs_mfma<<<dim3(NN/64, NN), 256, 0, stream>>>(A, Bm, ln_g, ln_b, W2p, b2, W3, b3, out);
}

// Round 4
// 222.103 us; speedup vs baseline: 6.9677x; 2.4819x over previous
//
#include <hip/hip_runtime.h>
#include <math.h>

#define NN 2048
#define HID 128
#define HID2 64
#define NP ((NN*(NN-1))/2)   // 2096128

typedef __bf16 bf16x8 __attribute__((ext_vector_type(8)));
typedef float  f32x4  __attribute__((ext_vector_type(4)));

// Kernel 1: per node row, fused h = relu(X@Wt + bt); A = h@W1[:128] + b1; B = h@W1[128:]
__global__ __launch_bounds__(128) void precompute_AB(
    const float* __restrict__ X, const float* __restrict__ Wt, const float* __restrict__ bt,
    const float* __restrict__ W1, const float* __restrict__ b1,
    float* __restrict__ A, float* __restrict__ B)
{
    __shared__ float x_s[HID];
    __shared__ float h_s[HID];
    const int row = blockIdx.x;
    const int c = threadIdx.x;
    x_s[c] = X[row*HID + c];
    __syncthreads();
    float hc = bt[c];
    #pragma unroll 8
    for (int k = 0; k < HID; ++k) hc = fmaf(x_s[k], Wt[k*HID + c], hc);
    h_s[c] = fmaxf(hc, 0.f);
    __syncthreads();
    float a = b1[c];
    float bsum = 0.f;
    #pragma unroll 8
    for (int k = 0; k < HID; ++k) {
        float hk = h_s[k];
        a    = fmaf(hk, W1[k*HID + c], a);
        bsum = fmaf(hk, W1[(HID + k)*HID + c], bsum);
    }
    A[row*HID + c] = a;
    B[row*HID + c] = bsum;
}

// Kernel 1b: pack W2 (fp32 [128][64]) into bf16 fragment order.
// frag (ks,nt), lane l, elem e  <-  W2[ks*32+(l>>4)*8+e][nt*16+(l&15)]
// Used as the *A* operand: A[m=channel_local][k] = W2[k][nt*16+m].
__global__ __launch_bounds__(256) void pack_W2(const float* __restrict__ W2,
                                               __bf16* __restrict__ W2p)
{
    const int t = threadIdx.x;
    for (int fs = t; fs < 16*64; fs += 256) {   // 16 frags x 64 lanes
        const int frag = fs >> 6, lane = fs & 63;
        const int ks = frag >> 2, nt = frag & 3;
        const int kbase = ks*32 + (lane >> 4)*8;
        const int col   = nt*16 + (lane & 15);
        #pragma unroll
        for (int e = 0; e < 8; ++e)
            W2p[fs*8 + e] = (__bf16)W2[(kbase + e)*HID2 + col];
    }
}

// Kernel 2: triangular grid of (i, 256-j) tiles; 4 waves/block; 64 pairs/wave
// as 4 independent 16-pair sub-blocks. mfma(W2frag, znfrag) puts pair on the
// D column axis -> epilogue reduce is just 2 shuffles.
__global__ __launch_bounds__(256, 2) void pairs_mfma(
    const float* __restrict__ A, const float* __restrict__ B,
    const float* __restrict__ ln_g, const float* __restrict__ ln_b,
    const __bf16* __restrict__ W2p, const float* __restrict__ b2,
    const float* __restrict__ W3, const float* __restrict__ b3,
    float* __restrict__ out)
{
    // ---- decode linear tile id -> (i, jb) over upper-triangular tiles ----
    int t = blockIdx.x;
    int q = 0, base = 0;
    while (q < 7 && t >= base + 256*(8 - q)) { base += 256*(8 - q); ++q; }
    const int idx = t - base;
    const int den = 8 - q;
    const int i  = (q << 8) + idx / den;
    const int jb = q + idx % den;

    const int w    = threadIdx.x >> 6;
    const int lane = threadIdx.x & 63;
    const int jw0  = (jb << 8) + (w << 6);       // this wave's 64 j's
    if (jw0 + 63 < i) return;                    // keep the j==i (diag) wave alive

    const int p16 = lane & 15;
    const int g4  = lane >> 4;

    const float* __restrict__ Ar = A + (size_t)i * HID;

    // A row slice this lane needs: k = ks*32 + g4*8 + e
    float a[4][8];
    #pragma unroll
    for (int ks = 0; ks < 4; ++ks) {
        const int kb = ks*32 + g4*8;
        f32x4 a0 = *(const f32x4*)(Ar + kb);
        f32x4 a1 = *(const f32x4*)(Ar + kb + 4);
        #pragma unroll
        for (int e = 0; e < 4; ++e) { a[ks][e] = a0[e]; a[ks][4+e] = a1[e]; }
    }

    // ---- per sub-block: z = A[i]+B[j], LN, relu, -> bf16 B-fragments ----
    bf16x8 af[4][4];   // [sub][ks]
    #pragma unroll
    for (int s = 0; s < 4; ++s) {
        const int j = jw0 + s*16 + p16;
        const float* __restrict__ Br = B + (size_t)j * HID;
        float z[4][8];
        #pragma unroll
        for (int ks = 0; ks < 4; ++ks) {
            const int kb = ks*32 + g4*8;
            f32x4 b0 = *(const f32x4*)(Br + kb);
            f32x4 b1 = *(const f32x4*)(Br + kb + 4);
            #pragma unroll
            for (int e = 0; e < 4; ++e) { z[ks][e] = a[ks][e] + b0[e]; z[ks][4+e] = a[ks][4+e] + b1[e]; }
        }
        float s1 = 0.f, s2 = 0.f;
        #pragma unroll
        for (int ks = 0; ks < 4; ++ks)
            #pragma unroll
            for (int e = 0; e < 8; ++e) { s1 += z[ks][e]; s2 = fmaf(z[ks][e], z[ks][e], s2); }
        s1 += __shfl_xor(s1, 16); s1 += __shfl_xor(s1, 32);
        s2 += __shfl_xor(s2, 16); s2 += __shfl_xor(s2, 32);
        const float mu   = s1 * (1.f/HID);
        const float rstd = rsqrtf(s2*(1.f/HID) - mu*mu + 1e-5f);

        #pragma unroll
        for (int ks = 0; ks < 4; ++ks) {
            const int kb = ks*32 + g4*8;
            f32x4 g0 = *(const f32x4*)(ln_g + kb);
            f32x4 g1 = *(const f32x4*)(ln_g + kb + 4);
            f32x4 l0 = *(const f32x4*)(ln_b + kb);
            f32x4 l1 = *(const f32x4*)(ln_b + kb + 4);
            #pragma unroll
            for (int e = 0; e < 4; ++e) {
                float c1a = rstd * g0[e];
                float c1b = rstd * g1[e];
                float zn0 = fmaxf(fmaf(z[ks][e],   c1a, fmaf(-mu, c1a, l0[e])), 0.f);
                float zn1 = fmaxf(fmaf(z[ks][4+e], c1b, fmaf(-mu, c1b, l1[e])), 0.f);
                af[s][ks][e]   = (__bf16)zn0;
                af[s][ks][4+e] = (__bf16)zn1;
            }
        }
    }

    // ---- MFMA: acc[s][nt] = W2^T(16ch x 32k) @ zn(32k x 16pair) ----
    f32x4 acc[4][4];
    #pragma unroll
    for (int s = 0; s < 4; ++s)
        #pragma unroll
        for (int nt = 0; nt < 4; ++nt) acc[s][nt] = (f32x4){0.f,0.f,0.f,0.f};
    #pragma unroll
    for (int ks = 0; ks < 4; ++ks) {
        #pragma unroll
        for (int nt = 0; nt < 4; ++nt) {
            bf16x8 wf = *(const bf16x8*)(W2p + ((size_t)((ks*4 + nt)*64 + lane)) * 8);
            #pragma unroll
            for (int s = 0; s < 4; ++s)
                acc[s][nt] = __builtin_amdgcn_mfma_f32_16x16x32_bf16(wf, af[s][ks], acc[s][nt], 0, 0, 0);
        }
    }

    // ---- epilogue: lane holds channels (nt*16+g4*4+r) of pair p16 ----
    float* probs = out;
    float* pi    = out + NP;
    float* adj   = out + 3*(size_t)NP;
    const float b3v = b3[0];

    #pragma unroll
    for (int s = 0; s < 4; ++s) {
        float part = 0.f;
        #pragma unroll
        for (int nt = 0; nt < 4; ++nt) {
            f32x4 b2v = *(const f32x4*)(b2 + nt*16 + g4*4);
            f32x4 w3v = *(const f32x4*)(W3 + nt*16 + g4*4);
            #pragma unroll
            for (int r = 0; r < 4; ++r)
                part = fmaf(fmaxf(acc[s][nt][r] + b2v[r], 0.f), w3v[r], part);
        }
        part += __shfl_xor(part, 16);
        part += __shfl_xor(part, 32);

        if (g4 == 0) {                       // lanes 0..15: one writer per pair
            const int j = jw0 + s*16 + p16;
            if (j == i) {
                adj[(size_t)i*NN + i] = 0.f;
            } else if (j > i && j < NN) {
                const float pr = 1.f / (1.f + __expf(-(part + b3v)));
                const int kpair = i*(NN-1) - (i*(i-1))/2 + (j - i - 1);
                probs[kpair]    = pr;
                pi[kpair]       = (float)i;
                pi[NP + kpair]  = (float)j;
                adj[(size_t)i*NN + j] = pr;
                adj[(size_t)j*NN + i] = pr;
            }
        }
    }
}

extern "C" void kernel_launch(void* const* d_in, const int* in_sizes, int n_in,
                              void* d_out, int out_size, void* d_ws, size_t ws_size,
                              hipStream_t stream) {
    const float* X    = (const float*)d_in[0];
    const float* Wt   = (const float*)d_in[1];
    const float* bt   = (const float*)d_in[2];
    const float* W1   = (const float*)d_in[3];
    const float* b1   = (const float*)d_in[4];
    const float* ln_g = (const float*)d_in[5];
    const float* ln_b = (const float*)d_in[6];
    const float* W2   = (const float*)d_in[7];
    const float* b2   = (const float*)d_in[8];
    const float* W3   = (const float*)d_in[9];
    const float* b3   = (const float*)d_in[10];
    float* out = (float*)d_out;

    float*  A   = (float*)d_ws;                      // [2048][128] f32
    float*  Bm  = A + (size_t)NN * HID;              // [2048][128] f32
    __bf16* W2p = (__bf16*)(Bm + (size_t)NN * HID);  // 16 frags x 64 lanes x 8 bf16

    precompute_AB<<<NN, HID, 0, stream>>>(X, Wt, bt, W1, b1, A, Bm);
    pack_W2<<<1, 256, 0, stream>>>(W2, W2p);

    const int nblk = 256 * 36;   // sum over q of 256*(8-q)
    pairs_mfma<<<nblk, 256, 0, stream>>>(A, Bm, ln_g, ln_b, W2p, b2, W3, b3, out);
}

// Round 5
// 171.379 us; speedup vs baseline: 9.0300x; 1.2960x over previous
//
#include <hip/hip_runtime.h>
#include <math.h>

#define NN 2048
#define HID 128
#define HID2 64
#define NP ((NN*(NN-1))/2)   // 2096128

typedef __bf16 bf16x8 __attribute__((ext_vector_type(8)));
typedef float  f32x4  __attribute__((ext_vector_type(4)));

// Kernel 1: per node row: h = relu(X@Wt+bt); a = h@W1top + b1; b = h@W1bot.
// Emits: A (f32 row-major), Abf (bf16 row-major), Bp (bf16 MFMA-fragment-packed),
// sa[row] = (sum a, sum a^2) from exact a, sb[row] = (sum b_r, sum b_r^2) from
// bf16-rounded b (consistent with what kernel 2 consumes).
__global__ __launch_bounds__(128) void precompute_AB(
    const float* __restrict__ X, const float* __restrict__ Wt, const float* __restrict__ bt,
    const float* __restrict__ W1, const float* __restrict__ b1,
    float* __restrict__ A, __bf16* __restrict__ Abf, __bf16* __restrict__ Bp,
    float2* __restrict__ sa, float2* __restrict__ sb)
{
    __shared__ float x_s[HID];
    __shared__ float h_s[HID];
    __shared__ float red[2][4];
    const int row = blockIdx.x;
    const int c = threadIdx.x;
    x_s[c] = X[row*HID + c];
    __syncthreads();
    float hc = bt[c];
    #pragma unroll 8
    for (int k = 0; k < HID; ++k) hc = fmaf(x_s[k], Wt[k*HID + c], hc);
    h_s[c] = fmaxf(hc, 0.f);
    __syncthreads();
    float a = b1[c];
    float bsum = 0.f;
    #pragma unroll 8
    for (int k = 0; k < HID; ++k) {
        float hk = h_s[k];
        a    = fmaf(hk, W1[k*HID + c], a);
        bsum = fmaf(hk, W1[(HID + k)*HID + c], bsum);
    }
    A[row*HID + c]   = a;
    Abf[row*HID + c] = (__bf16)a;
    const __bf16 bb = (__bf16)bsum;
    // fragment-packed: element (row, k=c): ks=c>>5, g4=(c>>3)&3, e=c&7
    {
        const int ks = c >> 5, g4 = (c >> 3) & 3, e = c & 7;
        Bp[(((size_t)(row >> 4)*4 + ks)*64 + g4*16 + (row & 15))*8 + e] = bb;
    }
    const float br = (float)bb;
    float r0 = a, r1 = a*a, r2 = br, r3 = br*br;
    #pragma unroll
    for (int m = 1; m <= 32; m <<= 1) {
        r0 += __shfl_xor(r0, m); r1 += __shfl_xor(r1, m);
        r2 += __shfl_xor(r2, m); r3 += __shfl_xor(r3, m);
    }
    if ((c & 63) == 0) {
        red[c >> 6][0] = r0; red[c >> 6][1] = r1; red[c >> 6][2] = r2; red[c >> 6][3] = r3;
    }
    __syncthreads();
    if (c == 0) {
        sa[row] = make_float2(red[0][0] + red[1][0], red[0][1] + red[1][1]);
        sb[row] = make_float2(red[0][2] + red[1][2], red[0][3] + red[1][3]);
    }
}

// Kernel 1b: pack W2 (fp32 [128][64]) into bf16 fragment order (A-operand, channels on rows).
__global__ __launch_bounds__(256) void pack_W2(const float* __restrict__ W2,
                                               __bf16* __restrict__ W2p)
{
    const int t = threadIdx.x;
    for (int fs = t; fs < 16*64; fs += 256) {
        const int frag = fs >> 6, lane = fs & 63;
        const int ks = frag >> 2, nt = frag & 3;
        const int kbase = ks*32 + (lane >> 4)*8;
        const int col   = nt*16 + (lane & 15);
        #pragma unroll
        for (int e = 0; e < 8; ++e)
            W2p[fs*8 + e] = (__bf16)W2[(kbase + e)*HID2 + col];
    }
}

// Kernel 1c: pair_index is a pure function of indices — fill it separately.
__global__ __launch_bounds__(256) void fill_pi(float* __restrict__ pi)
{
    const int i = blockIdx.x;                       // 0..2046
    const size_t off = (size_t)i*(NN-1) - (size_t)i*(i-1)/2;
    const int cnt = NN - 1 - i;
    for (int t = threadIdx.x; t < cnt; t += 256) {
        pi[off + t]      = (float)i;
        pi[NP + off + t] = (float)(i + 1 + t);
    }
}

// Kernel 2: triangular tiles; 4 waves/block; 64 pairs/wave (4 sub-blocks of 16).
// Per sub: MFMA dot (broadcast-A) -> per-pair LN stats O(1) -> zn (5 ops/elem,
// no shuffles) -> 16 zn-MFMAs. Epilogue: 2 shuffles, lane<16 writes.
__global__ __launch_bounds__(256, 3) void pairs_mfma(
    const float* __restrict__ A, const __bf16* __restrict__ Abf,
    const __bf16* __restrict__ Bp,
    const float2* __restrict__ sa, const float2* __restrict__ sb,
    const float* __restrict__ ln_g, const float* __restrict__ ln_b,
    const __bf16* __restrict__ W2p, const float* __restrict__ b2,
    const float* __restrict__ W3, const float* __restrict__ b3,
    float* __restrict__ out)
{
    // decode linear tile id -> (i, jb) over upper-triangular 256x256 tiles
    int t = blockIdx.x;
    int q = 0, base = 0;
    while (q < 7 && t >= base + 256*(8 - q)) { base += 256*(8 - q); ++q; }
    const int idx = t - base;
    const int den = 8 - q;
    const int i  = (q << 8) + idx / den;
    const int jb = q + idx % den;

    const int w    = threadIdx.x >> 6;
    const int lane = threadIdx.x & 63;
    const int jw0  = (jb << 8) + (w << 6);
    if (jw0 + 63 < i) return;

    const int p16 = lane & 15;
    const int g4  = lane >> 4;

    // hoist A[i] slice (f32, exact) and its bf16 frags (broadcast A-operand)
    const float* __restrict__ Ar = A + (size_t)i * HID;
    float a[4][8];
    bf16x8 abf[4];
    #pragma unroll
    for (int ks = 0; ks < 4; ++ks) {
        const int kb = ks*32 + g4*8;
        f32x4 a0 = *(const f32x4*)(Ar + kb);
        f32x4 a1 = *(const f32x4*)(Ar + kb + 4);
        #pragma unroll
        for (int e = 0; e < 4; ++e) { a[ks][e] = a0[e]; a[ks][4+e] = a1[e]; }
        abf[ks] = *(const bf16x8*)(Abf + (size_t)i * HID + kb);
    }
    const float2 sav = sa[i];

    const bf16x8* __restrict__ Bpv = (const bf16x8*)Bp;

    f32x4 acc[4][4];
    #pragma unroll
    for (int s = 0; s < 4; ++s)
        #pragma unroll
        for (int nt = 0; nt < 4; ++nt) acc[s][nt] = (f32x4){0.f,0.f,0.f,0.f};

    #pragma unroll
    for (int s = 0; s < 4; ++s) {
        const int j16 = jw0 + s*16;
        // B fragments (packed, coalesced 16B/lane)
        bf16x8 bfr[4];
        #pragma unroll
        for (int ks = 0; ks < 4; ++ks)
            bfr[ks] = Bpv[((size_t)(j16 >> 4)*4 + ks)*64 + lane];

        // dot(A[i], B[j_p]) for all 16 pairs via broadcast-A MFMA
        f32x4 dacc = (f32x4){0.f,0.f,0.f,0.f};
        #pragma unroll
        for (int ks = 0; ks < 4; ++ks)
            dacc = __builtin_amdgcn_mfma_f32_16x16x32_bf16(abf[ks], bfr[ks], dacc, 0, 0, 0);

        // unpack b and form z during MFMA latency
        float z[4][8];
        #pragma unroll
        for (int ks = 0; ks < 4; ++ks)
            #pragma unroll
            for (int e = 0; e < 8; ++e) z[ks][e] = a[ks][e] + (float)bfr[ks][e];

        // O(1) LN stats for this lane's pair
        const float2 sbv = sb[j16 + p16];
        const float d    = dacc[0];
        const float mu   = (sav.x + sbv.x) * (1.f/HID);
        const float ez2  = (sav.y + sbv.y + 2.f*d) * (1.f/HID);
        const float rstd = rsqrtf(ez2 - mu*mu + 1e-5f);
        const float v    = -mu * rstd;

        // zn = relu(g*(rstd*z + v) + l) -> bf16 frags
        bf16x8 af[4];
        #pragma unroll
        for (int ks = 0; ks < 4; ++ks) {
            const int kb = ks*32 + g4*8;
            f32x4 g0 = *(const f32x4*)(ln_g + kb);
            f32x4 g1 = *(const f32x4*)(ln_g + kb + 4);
            f32x4 l0 = *(const f32x4*)(ln_b + kb);
            f32x4 l1 = *(const f32x4*)(ln_b + kb + 4);
            #pragma unroll
            for (int e = 0; e < 4; ++e) {
                float q0 = fmaf(rstd, z[ks][e],   v);
                float q1 = fmaf(rstd, z[ks][4+e], v);
                af[ks][e]   = (__bf16)fmaxf(fmaf(g0[e], q0, l0[e]), 0.f);
                af[ks][4+e] = (__bf16)fmaxf(fmaf(g1[e], q1, l1[e]), 0.f);
            }
        }

        // zn MFMAs: channels x pairs
        #pragma unroll
        for (int ks = 0; ks < 4; ++ks) {
            #pragma unroll
            for (int nt = 0; nt < 4; ++nt) {
                bf16x8 wf = *(const bf16x8*)(W2p + ((size_t)((ks*4 + nt)*64 + lane)) * 8);
                acc[s][nt] = __builtin_amdgcn_mfma_f32_16x16x32_bf16(wf, af[ks], acc[s][nt], 0, 0, 0);
            }
        }
    }

    // epilogue: lane holds channels (nt*16 + g4*4 + r) of pair p16
    float* probs = out;
    float* adj   = out + 3*(size_t)NP;
    const float b3v = b3[0];

    #pragma unroll
    for (int s = 0; s < 4; ++s) {
        float part = 0.f;
        #pragma unroll
        for (int nt = 0; nt < 4; ++nt) {
            f32x4 b2v = *(const f32x4*)(b2 + nt*16 + g4*4);
            f32x4 w3v = *(const f32x4*)(W3 + nt*16 + g4*4);
            #pragma unroll
            for (int r = 0; r < 4; ++r)
                part = fmaf(fmaxf(acc[s][nt][r] + b2v[r], 0.f), w3v[r], part);
        }
        part += __shfl_xor(part, 16);
        part += __shfl_xor(part, 32);

        if (g4 == 0) {
            const int j = jw0 + s*16 + p16;
            if (j == i) {
                adj[(size_t)i*NN + i] = 0.f;
            } else if (j > i) {
                const float pr = 1.f / (1.f + __expf(-(part + b3v)));
                const int kpair = i*(NN-1) - (i*(i-1))/2 + (j - i - 1);
                probs[kpair] = pr;
                adj[(size_t)i*NN + j] = pr;
                adj[(size_t)j*NN + i] = pr;
            }
        }
    }
}

extern "C" void kernel_launch(void* const* d_in, const int* in_sizes, int n_in,
                              void* d_out, int out_size, void* d_ws, size_t ws_size,
                              hipStream_t stream) {
    const float* X    = (const float*)d_in[0];
    const float* Wt   = (const float*)d_in[1];
    const float* bt   = (const float*)d_in[2];
    const float* W1   = (const float*)d_in[3];
    const float* b1   = (const float*)d_in[4];
    const float* ln_g = (const float*)d_in[5];
    const float* ln_b = (const float*)d_in[6];
    const float* W2   = (const float*)d_in[7];
    const float* b2   = (const float*)d_in[8];
    const float* W3   = (const float*)d_in[9];
    const float* b3   = (const float*)d_in[10];
    float* out = (float*)d_out;

    float*  A   = (float*)d_ws;                        // 2048*128 f32
    float2* sa  = (float2*)(A + (size_t)NN * HID);     // 2048 float2
    float2* sb  = sa + NN;                             // 2048 float2
    __bf16* Abf = (__bf16*)(sb + NN);                  // 2048*128 bf16
    __bf16* Bp  = Abf + (size_t)NN * HID;              // 2048*128 bf16 (packed)
    __bf16* W2p = Bp  + (size_t)NN * HID;              // 16*64*8 bf16

    precompute_AB<<<NN, HID, 0, stream>>>(X, Wt, bt, W1, b1, A, Abf, Bp, sa, sb);
    pack_W2<<<1, 256, 0, stream>>>(W2, W2p);
    fill_pi<<<NN-1, 256, 0, stream>>>(out + NP);

    const int nblk = 256 * 36;
    pairs_mfma<<<nblk, 256, 0, stream>>>(A, Abf, Bp, sa, sb, ln_g, ln_b, W2p, b2, W3, b3, out);
}